// Round 1
// baseline (31020.789 us; speedup 1.0000x reference)
//
#include <hip/hip_runtime.h>

#define NN 50000
#define NE 600000

// ---------------- workspace layout (bytes) ----------------
static const size_t OFF_DEG    = 0;                         // 2*NN ints (deg_out, deg_in)
static const size_t OFF_NRM_O  = (size_t)8 * NN;            // NN floats
static const size_t OFF_NRM_I  = (size_t)12 * NN;           // NN floats
static const size_t OFF_STATS  = (size_t)16 * NN;           // 512 floats
static const size_t OFF_ZONE   = 1048576;                   // 1 MiB aligned big zone
static const size_t OFF_H0   = OFF_ZONE + 0;                // NN*48*4
static const size_t OFF_AGG1 = OFF_ZONE + 9600000;          // NN*48*4
static const size_t OFF_X1   = OFF_ZONE + 19200000;         // NN*128*4 (y1 then x1 in-place)
static const size_t OFF_T2   = OFF_ZONE + 44800000;         // NN*64*4
static const size_t OFF_PRE  = OFF_ZONE + 0;                // [2][NN][128] overlays h0..t2 (dead by then)
static const size_t OFF_AGG2 = OFF_ZONE + 57600000;         // NN*64*4 (y2 in-place)
static const size_t OFF_X2   = OFF_ZONE + 70400000;         // NN*64*4
static const size_t OFF_X3L  = OFF_ZONE + 83200000;         // NN*64*4 (x3 in-place)

__global__ void k_deg(const int* __restrict__ src, const int* __restrict__ dst,
                      int* __restrict__ deg_out, int* __restrict__ deg_in) {
    int e = blockIdx.x * blockDim.x + threadIdx.x;
    if (e < NE) {
        atomicAdd(&deg_out[src[e]], 1);
        atomicAdd(&deg_in[dst[e]], 1);
    }
}

__global__ void k_h0(const float* __restrict__ x, const int* __restrict__ nid,
                     const float* __restrict__ emb,
                     const int* __restrict__ deg_out, const int* __restrict__ deg_in,
                     float* __restrict__ nrm_out, float* __restrict__ nrm_in,
                     float* __restrict__ h0) {
    int n = blockIdx.x * blockDim.x + threadIdx.x;
    if (n >= NN) return;
    nrm_out[n] = rsqrtf((float)(deg_out[n] + 1));
    nrm_in[n]  = rsqrtf((float)(deg_in[n] + 1));
    const float* xr = x + (size_t)n * 35;
    float* hr = h0 + (size_t)n * 48;
    #pragma unroll
    for (int k = 0; k < 35; k++) hr[k] = xr[k];
    const float* er = emb + (size_t)nid[n] * 10;
    #pragma unroll
    for (int k = 0; k < 10; k++) hr[35 + k] = er[k];
    hr[45] = 0.f; hr[46] = 0.f; hr[47] = 0.f;
}

__global__ void k_scatter1(const int* __restrict__ src, const int* __restrict__ dst,
                           const float* __restrict__ h0, const float* __restrict__ nrm_out,
                           float* __restrict__ agg1) {
    long long t = (long long)blockIdx.x * blockDim.x + threadIdx.x;
    int e = (int)(t >> 2), q = (int)(t & 3);
    if (e >= NE) return;
    int s = src[e], d = dst[e];
    float sc = nrm_out[s];
    const float4* hr = (const float4*)(h0 + (size_t)s * 48) + q * 3;
    float* ar = agg1 + (size_t)d * 48 + q * 12;
    #pragma unroll
    for (int i = 0; i < 3; i++) {
        float4 v = hr[i];
        atomicAdd(ar + i * 4 + 0, v.x * sc);
        atomicAdd(ar + i * 4 + 1, v.y * sc);
        atomicAdd(ar + i * 4 + 2, v.z * sc);
        atomicAdd(ar + i * 4 + 3, v.w * sc);
    }
}

__global__ void k_y1(const float* __restrict__ h0, const float* __restrict__ agg1,
                     const float* __restrict__ nrm_out, const float* __restrict__ nrm_in,
                     const float* __restrict__ W1, const float* __restrict__ b1,
                     float* __restrict__ y1) {
    __shared__ float v[48];
    int n = blockIdx.x, o = threadIdx.x;
    if (o < 48) {
        v[o] = (agg1[(size_t)n * 48 + o] + h0[(size_t)n * 48 + o] * nrm_out[n]) * nrm_in[n];
    }
    __syncthreads();
    float acc = b1[o];
    #pragma unroll
    for (int k = 0; k < 45; k++) acc += v[k] * W1[k * 128 + o];
    y1[(size_t)n * 128 + o] = acc;
}

template<int F>
__global__ void k_red(const float* __restrict__ y, float* __restrict__ stats) {
    const int parts = 256 / F;
    __shared__ float s1[256], s2[256];
    int tid = threadIdx.x;
    int o = tid % F, p = tid / F;
    float a = 0.f, b = 0.f;
    int n0 = blockIdx.x * 512;
    int n1 = n0 + 512; if (n1 > NN) n1 = NN;
    for (int n = n0 + p; n < n1; n += parts) {
        float v = y[(size_t)n * F + o];
        a += v; b += v * v;
    }
    s1[tid] = a; s2[tid] = b;
    __syncthreads();
    if (p == 0) {
        #pragma unroll
        for (int pp = 1; pp < parts; pp++) { a += s1[pp * F + o]; b += s2[pp * F + o]; }
        atomicAdd(&stats[o], a);
        atomicAdd(&stats[F + o], b);
    }
}

__global__ void k_x1(const float* __restrict__ h0, const float* __restrict__ sc1W,
                     const float* __restrict__ sc1b, const float* __restrict__ g,
                     const float* __restrict__ bb, const float* __restrict__ stats,
                     float* __restrict__ y1x1) {
    __shared__ float hr[48];
    int n = blockIdx.x, o = threadIdx.x;
    if (o < 48) hr[o] = h0[(size_t)n * 48 + o];
    __syncthreads();
    float mu = stats[o] * (1.f / NN);
    float var = stats[128 + o] * (1.f / NN) - mu * mu;
    float istd = rsqrtf(var + 1e-5f);
    float acc = sc1b[o];
    #pragma unroll
    for (int k = 0; k < 45; k++) acc += hr[k] * sc1W[o * 45 + k];
    float v = (y1x1[(size_t)n * 128 + o] - mu) * istd * g[o] + bb[o] + acc;
    y1x1[(size_t)n * 128 + o] = v > 0.f ? v : 0.f;
}

__global__ void k_t2(const float* __restrict__ x1, const float* __restrict__ W2,
                     const float* __restrict__ nrm_out, float* __restrict__ t2) {
    __shared__ float xr[128];
    int n = blockIdx.x, o = threadIdx.x;
    xr[o] = x1[(size_t)n * 128 + o];
    xr[o + 64] = x1[(size_t)n * 128 + o + 64];
    __syncthreads();
    float acc = 0.f;
    #pragma unroll
    for (int k = 0; k < 128; k++) acc += xr[k] * W2[k * 64 + o];
    t2[(size_t)n * 64 + o] = acc * nrm_out[n];
}

__global__ void k_scatter2(const int* __restrict__ src, const int* __restrict__ dst,
                           const float* __restrict__ t2, float* __restrict__ agg2) {
    long long t = (long long)blockIdx.x * blockDim.x + threadIdx.x;
    int e = (int)(t >> 2), q = (int)(t & 3);
    if (e >= NE) return;
    int s = src[e], d = dst[e];
    const float4* tr = (const float4*)(t2 + (size_t)s * 64) + q * 4;
    float* ar = agg2 + (size_t)d * 64 + q * 16;
    #pragma unroll
    for (int i = 0; i < 4; i++) {
        float4 v = tr[i];
        atomicAdd(ar + i * 4 + 0, v.x);
        atomicAdd(ar + i * 4 + 1, v.y);
        atomicAdd(ar + i * 4 + 2, v.z);
        atomicAdd(ar + i * 4 + 3, v.w);
    }
}

__global__ void k_y2(float* __restrict__ agg2, const float* __restrict__ t2,
                     const float* __restrict__ nrm_in, const float* __restrict__ b2) {
    int i = blockIdx.x * blockDim.x + threadIdx.x;
    if (i >= NN * 64) return;
    int n = i >> 6, o = i & 63;
    agg2[i] = (agg2[i] + t2[i]) * nrm_in[n] + b2[o];
}

__global__ void k_x2(const float* __restrict__ x1, const float* __restrict__ y2,
                     const float* __restrict__ sc2W, const float* __restrict__ sc2b,
                     const float* __restrict__ g, const float* __restrict__ bb,
                     const float* __restrict__ stats, float* __restrict__ x2) {
    __shared__ float xr[128];
    int n = blockIdx.x, o = threadIdx.x;
    xr[o] = x1[(size_t)n * 128 + o];
    xr[o + 64] = x1[(size_t)n * 128 + o + 64];
    __syncthreads();
    float mu = stats[o] * (1.f / NN);
    float var = stats[64 + o] * (1.f / NN) - mu * mu;
    float istd = rsqrtf(var + 1e-5f);
    float acc = sc2b[o];
    #pragma unroll
    for (int k = 0; k < 128; k++) acc += xr[k] * sc2W[o * 128 + k];
    float v = (y2[(size_t)n * 64 + o] - mu) * istd * g[o] + bb[o] + acc;
    x2[(size_t)n * 64 + o] = v > 0.f ? v : 0.f;
}

__global__ void k_pre(const float* __restrict__ x2,
                      const float* __restrict__ Wf, const float* __restrict__ bif, const float* __restrict__ bhf,
                      const float* __restrict__ Wb, const float* __restrict__ bib, const float* __restrict__ bhb,
                      float* __restrict__ pre) {
    __shared__ float xr[64];
    int n = blockIdx.x, t = threadIdx.x;
    int j = t & 127, dir = t >> 7;
    if (t < 64) xr[t] = x2[(size_t)n * 64 + t];
    __syncthreads();
    const float* W = dir ? Wb : Wf;
    float acc = dir ? (bib[j] + bhb[j]) : (bif[j] + bhf[j]);
    #pragma unroll
    for (int k = 0; k < 64; k++) acc += xr[k] * W[j * 64 + k];
    pre[((size_t)dir * NN + n) * 128 + j] = acc;
}

static __device__ __forceinline__ float sigf(float v) { return 1.f / (1.f + __expf(-v)); }

__global__ void __launch_bounds__(64, 1)
k_lstm(const float* __restrict__ pre, const float* __restrict__ Whh_f,
       const float* __restrict__ Whh_b, float* __restrict__ x3l) {
    int dir = blockIdx.x;
    const float* P = pre + (size_t)dir * NN * 128;
    const float* Whh = dir ? Whh_b : Whh_f;
    int lane = threadIdx.x;
    bool lower = lane < 32;
    float Wa[32], Wb[32];
    #pragma unroll
    for (int j = 0; j < 32; j++) {
        Wa[j] = Whh[lane * 32 + j];
        Wb[j] = Whh[(lane + 64) * 32 + j];
    }
    float hcur = 0.f, c = 0.f;
    int outofs = dir * 32 + (lane & 31);
    float pa[8], pb[8];
    #pragma unroll
    for (int k = 0; k < 8; k++) {
        int t = dir ? (NN - 1 - k) : k;
        pa[k] = P[(size_t)t * 128 + lane];
        pb[k] = P[(size_t)t * 128 + 64 + lane];
    }
    for (int base = 0; base < NN; base += 8) {
        float na[8], nb[8];
        int nxt = (base + 8 < NN) ? (base + 8) : base;
        #pragma unroll
        for (int k = 0; k < 8; k++) {
            int s = nxt + k;
            int t = dir ? (NN - 1 - s) : s;
            na[k] = P[(size_t)t * 128 + lane];
            nb[k] = P[(size_t)t * 128 + 64 + lane];
        }
        #pragma unroll
        for (int k = 0; k < 8; k++) {
            float a0 = 0.f, a1 = 0.f, a2 = 0.f, a3 = 0.f;
            float b0 = 0.f, b1 = 0.f, b2 = 0.f, b3 = 0.f;
            #pragma unroll
            for (int j = 0; j < 32; j += 4) {
                float h0_ = __shfl(hcur, j);
                float h1_ = __shfl(hcur, j + 1);
                float h2_ = __shfl(hcur, j + 2);
                float h3_ = __shfl(hcur, j + 3);
                a0 += Wa[j] * h0_;     b0 += Wb[j] * h0_;
                a1 += Wa[j + 1] * h1_; b1 += Wb[j + 1] * h1_;
                a2 += Wa[j + 2] * h2_; b2 += Wb[j + 2] * h2_;
                a3 += Wa[j + 3] * h3_; b3 += Wb[j + 3] * h3_;
            }
            float ga = pa[k] + ((a0 + a1) + (a2 + a3));
            float gb = pb[k] + ((b0 + b1) + (b2 + b3));
            float act_a = sigf(ga);
            float gbs = lower ? 2.f * gb : gb;
            float sg = sigf(gbs);
            float act_b = lower ? 2.f * sg - 1.f : sg;
            float xa = __shfl_xor(act_a, 32);
            float xb = __shfl_xor(act_b, 32);
            float i_ = lower ? act_a : xa;
            float f_ = lower ? xa : act_a;
            float g_ = lower ? act_b : xb;
            float o_ = lower ? xb : act_b;
            c = f_ * c + i_ * g_;
            float th = 2.f / (1.f + __expf(-2.f * c)) - 1.f;
            hcur = o_ * th;
            int s = base + k;
            int t = dir ? (NN - 1 - s) : s;
            if (lower) x3l[(size_t)t * 64 + outofs] = hcur;
        }
        #pragma unroll
        for (int k = 0; k < 8; k++) { pa[k] = na[k]; pb[k] = nb[k]; }
    }
}

__global__ void k_x3(const float* __restrict__ x2, const float* __restrict__ sc3W,
                     const float* __restrict__ sc3b, const float* __restrict__ g,
                     const float* __restrict__ bb, const float* __restrict__ stats,
                     float* __restrict__ x3l) {
    __shared__ float xr[64];
    int n = blockIdx.x, o = threadIdx.x;
    xr[o] = x2[(size_t)n * 64 + o];
    __syncthreads();
    float mu = stats[o] * (1.f / NN);
    float var = stats[64 + o] * (1.f / NN) - mu * mu;
    float istd = rsqrtf(var + 1e-5f);
    float acc = sc3b[o];
    #pragma unroll
    for (int k = 0; k < 64; k++) acc += xr[k] * sc3W[o * 64 + k];
    float v = (x3l[(size_t)n * 64 + o] - mu) * istd * g[o] + bb[o] + acc;
    x3l[(size_t)n * 64 + o] = v > 0.f ? v : 0.f;
}

__global__ void k_heads(const float* __restrict__ x3,
                        const float* __restrict__ a1W, const float* __restrict__ a1b,
                        const float* __restrict__ a2W, const float* __restrict__ a2b,
                        const float* __restrict__ c1W, const float* __restrict__ c1b,
                        const float* __restrict__ c2W, const float* __restrict__ c2b,
                        float* __restrict__ outp) {
    __shared__ float xr[64];
    int n = blockIdx.x, o = threadIdx.x;
    xr[o] = x3[(size_t)n * 64 + o];
    __syncthreads();
    float ta = a1b[o], tc = c1b[o];
    #pragma unroll
    for (int k = 0; k < 64; k++) {
        float xv = xr[k];
        ta += xv * a1W[o * 64 + k];
        tc += xv * c1W[o * 64 + k];
    }
    ta = ta > 0.f ? ta : 0.f;
    tc = tc > 0.f ? tc : 0.f;
    float va = ta * a2W[o], vc = tc * c2W[o];
    #pragma unroll
    for (int off = 32; off; off >>= 1) {
        va += __shfl_down(va, off);
        vc += __shfl_down(vc, off);
    }
    if (o == 0) {
        outp[n] = va + a2b[0];
        outp[NN + n] = vc + c2b[0];
    }
}

extern "C" void kernel_launch(void* const* d_in, const int* in_sizes, int n_in,
                              void* d_out, int out_size, void* d_ws, size_t ws_size,
                              hipStream_t stream) {
    const int*   src   = (const int*)  d_in[0];
    const int*   dst   = (const int*)  d_in[1];
    const float* x     = (const float*)d_in[2];
    const int*   nid   = (const int*)  d_in[3];
    const float* emb   = (const float*)d_in[4];
    const float* W1    = (const float*)d_in[5];
    const float* b1    = (const float*)d_in[6];
    const float* W2    = (const float*)d_in[7];
    const float* b2    = (const float*)d_in[8];
    const float* bn1g  = (const float*)d_in[9];
    const float* bn1b  = (const float*)d_in[10];
    const float* bn2g  = (const float*)d_in[11];
    const float* bn2b  = (const float*)d_in[12];
    const float* bn3g  = (const float*)d_in[13];
    const float* bn3b  = (const float*)d_in[14];
    const float* sc1W  = (const float*)d_in[15];
    const float* sc1b  = (const float*)d_in[16];
    const float* sc2W  = (const float*)d_in[17];
    const float* sc2b  = (const float*)d_in[18];
    const float* sc3W  = (const float*)d_in[19];
    const float* sc3b  = (const float*)d_in[20];
    const float* Wih_f = (const float*)d_in[21];
    const float* Whh_f = (const float*)d_in[22];
    const float* bih_f = (const float*)d_in[23];
    const float* bhh_f = (const float*)d_in[24];
    const float* Wih_b = (const float*)d_in[25];
    const float* Whh_b = (const float*)d_in[26];
    const float* bih_b = (const float*)d_in[27];
    const float* bhh_b = (const float*)d_in[28];
    const float* a1W   = (const float*)d_in[29];
    const float* a1b   = (const float*)d_in[30];
    const float* a2W   = (const float*)d_in[31];
    const float* a2b   = (const float*)d_in[32];
    const float* c1W   = (const float*)d_in[33];
    const float* c1b   = (const float*)d_in[34];
    const float* c2W   = (const float*)d_in[35];
    const float* c2b   = (const float*)d_in[36];
    float* outp = (float*)d_out;
    char* ws = (char*)d_ws;

    int*   deg_out = (int*)  (ws + OFF_DEG);
    int*   deg_in  = (int*)  (ws + OFF_DEG + 4 * (size_t)NN);
    float* nrm_out = (float*)(ws + OFF_NRM_O);
    float* nrm_in  = (float*)(ws + OFF_NRM_I);
    float* stats   = (float*)(ws + OFF_STATS);
    float* h0   = (float*)(ws + OFF_H0);
    float* agg1 = (float*)(ws + OFF_AGG1);
    float* x1   = (float*)(ws + OFF_X1);
    float* t2   = (float*)(ws + OFF_T2);
    float* pre  = (float*)(ws + OFF_PRE);
    float* agg2 = (float*)(ws + OFF_AGG2);
    float* x2   = (float*)(ws + OFF_X2);
    float* x3l  = (float*)(ws + OFF_X3L);

    hipMemsetAsync(ws + OFF_DEG, 0, 8 * (size_t)NN, stream);
    hipMemsetAsync(ws + OFF_STATS, 0, 512 * 4, stream);
    hipMemsetAsync(ws + OFF_AGG1, 0, (size_t)NN * 48 * 4, stream);
    hipMemsetAsync(ws + OFF_AGG2, 0, (size_t)NN * 64 * 4, stream);

    k_deg<<<(NE + 255) / 256, 256, 0, stream>>>(src, dst, deg_out, deg_in);
    k_h0<<<(NN + 255) / 256, 256, 0, stream>>>(x, nid, emb, deg_out, deg_in, nrm_out, nrm_in, h0);
    k_scatter1<<<(4 * NE) / 256, 256, 0, stream>>>(src, dst, h0, nrm_out, agg1);
    k_y1<<<NN, 128, 0, stream>>>(h0, agg1, nrm_out, nrm_in, W1, b1, x1);
    k_red<128><<<(NN + 511) / 512, 256, 0, stream>>>(x1, stats);
    k_x1<<<NN, 128, 0, stream>>>(h0, sc1W, sc1b, bn1g, bn1b, stats, x1);
    k_t2<<<NN, 64, 0, stream>>>(x1, W2, nrm_out, t2);
    k_scatter2<<<(4 * NE) / 256, 256, 0, stream>>>(src, dst, t2, agg2);
    k_y2<<<(NN * 64 + 255) / 256, 256, 0, stream>>>(agg2, t2, nrm_in, b2);
    k_red<64><<<(NN + 511) / 512, 256, 0, stream>>>(agg2, stats + 256);
    k_x2<<<NN, 64, 0, stream>>>(x1, agg2, sc2W, sc2b, bn2g, bn2b, stats + 256, x2);
    k_pre<<<NN, 256, 0, stream>>>(x2, Wih_f, bih_f, bhh_f, Wih_b, bih_b, bhh_b, pre);
    k_lstm<<<2, 64, 0, stream>>>(pre, Whh_f, Whh_b, x3l);
    k_red<64><<<(NN + 511) / 512, 256, 0, stream>>>(x3l, stats + 384);
    k_x3<<<NN, 64, 0, stream>>>(x2, sc3W, sc3b, bn3g, bn3b, stats + 384, x3l);
    k_heads<<<NN, 64, 0, stream>>>(x3l, a1W, a1b, a2W, a2b, c1W, c1b, c2W, c2b, outp);
}

// Round 2
// 22057.332 us; speedup vs baseline: 1.4064x; 1.4064x over previous
//
#include <hip/hip_runtime.h>

#define NN 50000
#define NE 600000

typedef __attribute__((ext_vector_type(2))) float f2;
typedef __attribute__((ext_vector_type(4))) float f4;

// ---------------- workspace layout (bytes) ----------------
static const size_t OFF_DEG    = 0;                         // 2*NN ints (deg_out, deg_in)
static const size_t OFF_NRM_O  = (size_t)8 * NN;            // NN floats
static const size_t OFF_NRM_I  = (size_t)12 * NN;           // NN floats
static const size_t OFF_STATS  = (size_t)16 * NN;           // 512 floats
static const size_t OFF_ZONE   = 1048576;                   // 1 MiB aligned big zone
static const size_t OFF_H0   = OFF_ZONE + 0;                // NN*48*4
static const size_t OFF_AGG1 = OFF_ZONE + 9600000;          // NN*48*4
static const size_t OFF_X1   = OFF_ZONE + 19200000;         // NN*128*4 (y1 then x1 in-place)
static const size_t OFF_T2   = OFF_ZONE + 44800000;         // NN*64*4
static const size_t OFF_PRE  = OFF_ZONE + 0;                // [2][NN][128] overlays h0..t2 (dead by then)
static const size_t OFF_AGG2 = OFF_ZONE + 57600000;         // NN*64*4 (y2 in-place)
static const size_t OFF_X2   = OFF_ZONE + 70400000;         // NN*64*4
static const size_t OFF_X3L  = OFF_ZONE + 83200000;         // NN*64*4 (x3 in-place)

__global__ void k_deg(const int* __restrict__ src, const int* __restrict__ dst,
                      int* __restrict__ deg_out, int* __restrict__ deg_in) {
    int e = blockIdx.x * blockDim.x + threadIdx.x;
    if (e < NE) {
        atomicAdd(&deg_out[src[e]], 1);
        atomicAdd(&deg_in[dst[e]], 1);
    }
}

__global__ void k_h0(const float* __restrict__ x, const int* __restrict__ nid,
                     const float* __restrict__ emb,
                     const int* __restrict__ deg_out, const int* __restrict__ deg_in,
                     float* __restrict__ nrm_out, float* __restrict__ nrm_in,
                     float* __restrict__ h0) {
    int n = blockIdx.x * blockDim.x + threadIdx.x;
    if (n >= NN) return;
    nrm_out[n] = rsqrtf((float)(deg_out[n] + 1));
    nrm_in[n]  = rsqrtf((float)(deg_in[n] + 1));
    const float* xr = x + (size_t)n * 35;
    float* hr = h0 + (size_t)n * 48;
    #pragma unroll
    for (int k = 0; k < 35; k++) hr[k] = xr[k];
    const float* er = emb + (size_t)nid[n] * 10;
    #pragma unroll
    for (int k = 0; k < 10; k++) hr[35 + k] = er[k];
    hr[45] = 0.f; hr[46] = 0.f; hr[47] = 0.f;
}

__global__ void k_scatter1(const int* __restrict__ src, const int* __restrict__ dst,
                           const float* __restrict__ h0, const float* __restrict__ nrm_out,
                           float* __restrict__ agg1) {
    long long t = (long long)blockIdx.x * blockDim.x + threadIdx.x;
    int e = (int)(t >> 2), q = (int)(t & 3);
    if (e >= NE) return;
    int s = src[e], d = dst[e];
    float sc = nrm_out[s];
    const float4* hr = (const float4*)(h0 + (size_t)s * 48) + q * 3;
    float* ar = agg1 + (size_t)d * 48 + q * 12;
    #pragma unroll
    for (int i = 0; i < 3; i++) {
        float4 v = hr[i];
        atomicAdd(ar + i * 4 + 0, v.x * sc);
        atomicAdd(ar + i * 4 + 1, v.y * sc);
        atomicAdd(ar + i * 4 + 2, v.z * sc);
        atomicAdd(ar + i * 4 + 3, v.w * sc);
    }
}

__global__ void k_y1(const float* __restrict__ h0, const float* __restrict__ agg1,
                     const float* __restrict__ nrm_out, const float* __restrict__ nrm_in,
                     const float* __restrict__ W1, const float* __restrict__ b1,
                     float* __restrict__ y1) {
    __shared__ float v[48];
    int n = blockIdx.x, o = threadIdx.x;
    if (o < 48) {
        v[o] = (agg1[(size_t)n * 48 + o] + h0[(size_t)n * 48 + o] * nrm_out[n]) * nrm_in[n];
    }
    __syncthreads();
    float acc = b1[o];
    #pragma unroll
    for (int k = 0; k < 45; k++) acc += v[k] * W1[k * 128 + o];
    y1[(size_t)n * 128 + o] = acc;
}

template<int F>
__global__ void k_red(const float* __restrict__ y, float* __restrict__ stats) {
    const int parts = 256 / F;
    __shared__ float s1[256], s2[256];
    int tid = threadIdx.x;
    int o = tid % F, p = tid / F;
    float a = 0.f, b = 0.f;
    int n0 = blockIdx.x * 512;
    int n1 = n0 + 512; if (n1 > NN) n1 = NN;
    for (int n = n0 + p; n < n1; n += parts) {
        float v = y[(size_t)n * F + o];
        a += v; b += v * v;
    }
    s1[tid] = a; s2[tid] = b;
    __syncthreads();
    if (p == 0) {
        #pragma unroll
        for (int pp = 1; pp < parts; pp++) { a += s1[pp * F + o]; b += s2[pp * F + o]; }
        atomicAdd(&stats[o], a);
        atomicAdd(&stats[F + o], b);
    }
}

__global__ void k_x1(const float* __restrict__ h0, const float* __restrict__ sc1W,
                     const float* __restrict__ sc1b, const float* __restrict__ g,
                     const float* __restrict__ bb, const float* __restrict__ stats,
                     float* __restrict__ y1x1) {
    __shared__ float hr[48];
    int n = blockIdx.x, o = threadIdx.x;
    if (o < 48) hr[o] = h0[(size_t)n * 48 + o];
    __syncthreads();
    float mu = stats[o] * (1.f / NN);
    float var = stats[128 + o] * (1.f / NN) - mu * mu;
    float istd = rsqrtf(var + 1e-5f);
    float acc = sc1b[o];
    #pragma unroll
    for (int k = 0; k < 45; k++) acc += hr[k] * sc1W[o * 45 + k];
    float v = (y1x1[(size_t)n * 128 + o] - mu) * istd * g[o] + bb[o] + acc;
    y1x1[(size_t)n * 128 + o] = v > 0.f ? v : 0.f;
}

__global__ void k_t2(const float* __restrict__ x1, const float* __restrict__ W2,
                     const float* __restrict__ nrm_out, float* __restrict__ t2) {
    __shared__ float xr[128];
    int n = blockIdx.x, o = threadIdx.x;
    xr[o] = x1[(size_t)n * 128 + o];
    xr[o + 64] = x1[(size_t)n * 128 + o + 64];
    __syncthreads();
    float acc = 0.f;
    #pragma unroll
    for (int k = 0; k < 128; k++) acc += xr[k] * W2[k * 64 + o];
    t2[(size_t)n * 64 + o] = acc * nrm_out[n];
}

__global__ void k_scatter2(const int* __restrict__ src, const int* __restrict__ dst,
                           const float* __restrict__ t2, float* __restrict__ agg2) {
    long long t = (long long)blockIdx.x * blockDim.x + threadIdx.x;
    int e = (int)(t >> 2), q = (int)(t & 3);
    if (e >= NE) return;
    int s = src[e], d = dst[e];
    const float4* tr = (const float4*)(t2 + (size_t)s * 64) + q * 4;
    float* ar = agg2 + (size_t)d * 64 + q * 16;
    #pragma unroll
    for (int i = 0; i < 4; i++) {
        float4 v = tr[i];
        atomicAdd(ar + i * 4 + 0, v.x);
        atomicAdd(ar + i * 4 + 1, v.y);
        atomicAdd(ar + i * 4 + 2, v.z);
        atomicAdd(ar + i * 4 + 3, v.w);
    }
}

__global__ void k_y2(float* __restrict__ agg2, const float* __restrict__ t2,
                     const float* __restrict__ nrm_in, const float* __restrict__ b2) {
    int i = blockIdx.x * blockDim.x + threadIdx.x;
    if (i >= NN * 64) return;
    int n = i >> 6, o = i & 63;
    agg2[i] = (agg2[i] + t2[i]) * nrm_in[n] + b2[o];
}

__global__ void k_x2(const float* __restrict__ x1, const float* __restrict__ y2,
                     const float* __restrict__ sc2W, const float* __restrict__ sc2b,
                     const float* __restrict__ g, const float* __restrict__ bb,
                     const float* __restrict__ stats, float* __restrict__ x2) {
    __shared__ float xr[128];
    int n = blockIdx.x, o = threadIdx.x;
    xr[o] = x1[(size_t)n * 128 + o];
    xr[o + 64] = x1[(size_t)n * 128 + o + 64];
    __syncthreads();
    float mu = stats[o] * (1.f / NN);
    float var = stats[64 + o] * (1.f / NN) - mu * mu;
    float istd = rsqrtf(var + 1e-5f);
    float acc = sc2b[o];
    #pragma unroll
    for (int k = 0; k < 128; k++) acc += xr[k] * sc2W[o * 128 + k];
    float v = (y2[(size_t)n * 64 + o] - mu) * istd * g[o] + bb[o] + acc;
    x2[(size_t)n * 64 + o] = v > 0.f ? v : 0.f;
}

__global__ void k_pre(const float* __restrict__ x2,
                      const float* __restrict__ Wf, const float* __restrict__ bif, const float* __restrict__ bhf,
                      const float* __restrict__ Wb, const float* __restrict__ bib, const float* __restrict__ bhb,
                      float* __restrict__ pre) {
    __shared__ float xr[64];
    int n = blockIdx.x, t = threadIdx.x;
    int j = t & 127, dir = t >> 7;
    if (t < 64) xr[t] = x2[(size_t)n * 64 + t];
    __syncthreads();
    const float* W = dir ? Wb : Wf;
    float acc = dir ? (bib[j] + bhb[j]) : (bif[j] + bhf[j]);
    #pragma unroll
    for (int k = 0; k < 64; k++) acc += xr[k] * W[j * 64 + k];
    pre[((size_t)dir * NN + n) * 128 + j] = acc;
}

// 2 blocks (one per direction), 128 threads = 2 waves. Thread t owns gate row t.
// Rows 0-31 = i, 32-63 = f (wave 0); 64-95 = g, 96-127 = o (wave 1).
// h lives in per-wave LDS (double-buffered); gates exchanged via double-buffered
// LDS with ONE barrier per step. 32 weights/lane -> no spill pressure.
__global__ void __launch_bounds__(128, 1)
k_lstm2(const float* __restrict__ pre, const float* __restrict__ Whh_f,
        const float* __restrict__ Whh_b, float* __restrict__ x3l) {
    const int dir = blockIdx.x;
    const float* __restrict__ P = pre + (size_t)dir * NN * 128;
    const float* __restrict__ Whh = dir ? Whh_b : Whh_f;
    const int r = threadIdx.x;          // gate row 0..127
    const int wave = r >> 6;
    const int lane = r & 63;
    const bool is_g = (r >> 5) == 2;    // rows 64..95 -> tanh

    __shared__ float act_s[2][128];
    __shared__ f4 h_s[2][2][8];         // [wave][buf][32 floats]

    // 16 packed weight pairs per lane: Whh row r (layout (128,32) row-major)
    f2 w[16];
    #pragma unroll
    for (int m = 0; m < 16; m++) w[m] = ((const f2*)(Whh + (size_t)r * 32))[m];

    if (lane < 32) ((float*)(h_s[wave][0]))[lane] = 0.f;

    float c = 0.f;
    float p_[8], n_[8];
    #pragma unroll
    for (int k = 0; k < 8; k++) {
        int t = dir ? (NN - 1 - k) : k;
        p_[k] = P[(size_t)t * 128 + r];
    }
    __syncthreads();

    for (int base = 0; base < NN; base += 8) {
        int nxt = (base + 8 < NN) ? base + 8 : base;
        #pragma unroll
        for (int k = 0; k < 8; k++) {
            int s = nxt + k;
            int t = dir ? (NN - 1 - s) : s;
            n_[k] = P[(size_t)t * 128 + r];
        }
        #pragma unroll
        for (int k = 0; k < 8; k++) {
            const int s = base + k;
            const int b = s & 1;
            // g4 = pre + h . W[r,:]
            f2 acc0 = {0.f, 0.f}, acc1 = {0.f, 0.f};
            #pragma unroll
            for (int m = 0; m < 8; m++) {
                f4 hv = h_s[wave][b][m];
                acc0 += w[2 * m] * hv.xy;
                acc1 += w[2 * m + 1] * hv.zw;
            }
            f2 a2 = acc0 + acc1;
            float g4 = p_[k] + a2.x + a2.y;
            float xs = is_g ? 2.f * g4 : g4;
            float e = 1.f / (1.f + __expf(-xs));
            float act = is_g ? 2.f * e - 1.f : e;     // tanh for g rows
            act_s[b][r] = act;
            __syncthreads();
            if (lane < 32) {
                float iv = act_s[b][lane];
                float fv = act_s[b][32 + lane];
                float gv = act_s[b][64 + lane];
                float ov = act_s[b][96 + lane];
                c = fv * c + iv * gv;
                float th = 2.f / (1.f + __expf(-2.f * c)) - 1.f;
                float h = ov * th;
                ((float*)(h_s[wave][b ^ 1]))[lane] = h;   // next step's h
                if (wave == 0) {
                    int t = dir ? (NN - 1 - s) : s;
                    x3l[(size_t)t * 64 + dir * 32 + lane] = h;
                }
            }
        }
        #pragma unroll
        for (int k = 0; k < 8; k++) p_[k] = n_[k];
    }
}

__global__ void k_x3(const float* __restrict__ x2, const float* __restrict__ sc3W,
                     const float* __restrict__ sc3b, const float* __restrict__ g,
                     const float* __restrict__ bb, const float* __restrict__ stats,
                     float* __restrict__ x3l) {
    __shared__ float xr[64];
    int n = blockIdx.x, o = threadIdx.x;
    xr[o] = x2[(size_t)n * 64 + o];
    __syncthreads();
    float mu = stats[o] * (1.f / NN);
    float var = stats[64 + o] * (1.f / NN) - mu * mu;
    float istd = rsqrtf(var + 1e-5f);
    float acc = sc3b[o];
    #pragma unroll
    for (int k = 0; k < 64; k++) acc += xr[k] * sc3W[o * 64 + k];
    float v = (x3l[(size_t)n * 64 + o] - mu) * istd * g[o] + bb[o] + acc;
    x3l[(size_t)n * 64 + o] = v > 0.f ? v : 0.f;
}

__global__ void k_heads(const float* __restrict__ x3,
                        const float* __restrict__ a1W, const float* __restrict__ a1b,
                        const float* __restrict__ a2W, const float* __restrict__ a2b,
                        const float* __restrict__ c1W, const float* __restrict__ c1b,
                        const float* __restrict__ c2W, const float* __restrict__ c2b,
                        float* __restrict__ outp) {
    __shared__ float xr[64];
    int n = blockIdx.x, o = threadIdx.x;
    xr[o] = x3[(size_t)n * 64 + o];
    __syncthreads();
    float ta = a1b[o], tc = c1b[o];
    #pragma unroll
    for (int k = 0; k < 64; k++) {
        float xv = xr[k];
        ta += xv * a1W[o * 64 + k];
        tc += xv * c1W[o * 64 + k];
    }
    ta = ta > 0.f ? ta : 0.f;
    tc = tc > 0.f ? tc : 0.f;
    float va = ta * a2W[o], vc = tc * c2W[o];
    #pragma unroll
    for (int off = 32; off; off >>= 1) {
        va += __shfl_down(va, off);
        vc += __shfl_down(vc, off);
    }
    if (o == 0) {
        outp[n] = va + a2b[0];
        outp[NN + n] = vc + c2b[0];
    }
}

extern "C" void kernel_launch(void* const* d_in, const int* in_sizes, int n_in,
                              void* d_out, int out_size, void* d_ws, size_t ws_size,
                              hipStream_t stream) {
    const int*   src   = (const int*)  d_in[0];
    const int*   dst   = (const int*)  d_in[1];
    const float* x     = (const float*)d_in[2];
    const int*   nid   = (const int*)  d_in[3];
    const float* emb   = (const float*)d_in[4];
    const float* W1    = (const float*)d_in[5];
    const float* b1    = (const float*)d_in[6];
    const float* W2    = (const float*)d_in[7];
    const float* b2    = (const float*)d_in[8];
    const float* bn1g  = (const float*)d_in[9];
    const float* bn1b  = (const float*)d_in[10];
    const float* bn2g  = (const float*)d_in[11];
    const float* bn2b  = (const float*)d_in[12];
    const float* bn3g  = (const float*)d_in[13];
    const float* bn3b  = (const float*)d_in[14];
    const float* sc1W  = (const float*)d_in[15];
    const float* sc1b  = (const float*)d_in[16];
    const float* sc2W  = (const float*)d_in[17];
    const float* sc2b  = (const float*)d_in[18];
    const float* sc3W  = (const float*)d_in[19];
    const float* sc3b  = (const float*)d_in[20];
    const float* Wih_f = (const float*)d_in[21];
    const float* Whh_f = (const float*)d_in[22];
    const float* bih_f = (const float*)d_in[23];
    const float* bhh_f = (const float*)d_in[24];
    const float* Wih_b = (const float*)d_in[25];
    const float* Whh_b = (const float*)d_in[26];
    const float* bih_b = (const float*)d_in[27];
    const float* bhh_b = (const float*)d_in[28];
    const float* a1W   = (const float*)d_in[29];
    const float* a1b   = (const float*)d_in[30];
    const float* a2W   = (const float*)d_in[31];
    const float* a2b   = (const float*)d_in[32];
    const float* c1W   = (const float*)d_in[33];
    const float* c1b   = (const float*)d_in[34];
    const float* c2W   = (const float*)d_in[35];
    const float* c2b   = (const float*)d_in[36];
    float* outp = (float*)d_out;
    char* ws = (char*)d_ws;

    int*   deg_out = (int*)  (ws + OFF_DEG);
    int*   deg_in  = (int*)  (ws + OFF_DEG + 4 * (size_t)NN);
    float* nrm_out = (float*)(ws + OFF_NRM_O);
    float* nrm_in  = (float*)(ws + OFF_NRM_I);
    float* stats   = (float*)(ws + OFF_STATS);
    float* h0   = (float*)(ws + OFF_H0);
    float* agg1 = (float*)(ws + OFF_AGG1);
    float* x1   = (float*)(ws + OFF_X1);
    float* t2   = (float*)(ws + OFF_T2);
    float* pre  = (float*)(ws + OFF_PRE);
    float* agg2 = (float*)(ws + OFF_AGG2);
    float* x2   = (float*)(ws + OFF_X2);
    float* x3l  = (float*)(ws + OFF_X3L);

    hipMemsetAsync(ws + OFF_DEG, 0, 8 * (size_t)NN, stream);
    hipMemsetAsync(ws + OFF_STATS, 0, 512 * 4, stream);
    hipMemsetAsync(ws + OFF_AGG1, 0, (size_t)NN * 48 * 4, stream);
    hipMemsetAsync(ws + OFF_AGG2, 0, (size_t)NN * 64 * 4, stream);

    k_deg<<<(NE + 255) / 256, 256, 0, stream>>>(src, dst, deg_out, deg_in);
    k_h0<<<(NN + 255) / 256, 256, 0, stream>>>(x, nid, emb, deg_out, deg_in, nrm_out, nrm_in, h0);
    k_scatter1<<<(4 * NE) / 256, 256, 0, stream>>>(src, dst, h0, nrm_out, agg1);
    k_y1<<<NN, 128, 0, stream>>>(h0, agg1, nrm_out, nrm_in, W1, b1, x1);
    k_red<128><<<(NN + 511) / 512, 256, 0, stream>>>(x1, stats);
    k_x1<<<NN, 128, 0, stream>>>(h0, sc1W, sc1b, bn1g, bn1b, stats, x1);
    k_t2<<<NN, 64, 0, stream>>>(x1, W2, nrm_out, t2);
    k_scatter2<<<(4 * NE) / 256, 256, 0, stream>>>(src, dst, t2, agg2);
    k_y2<<<(NN * 64 + 255) / 256, 256, 0, stream>>>(agg2, t2, nrm_in, b2);
    k_red<64><<<(NN + 511) / 512, 256, 0, stream>>>(agg2, stats + 256);
    k_x2<<<NN, 64, 0, stream>>>(x1, agg2, sc2W, sc2b, bn2g, bn2b, stats + 256, x2);
    k_pre<<<NN, 256, 0, stream>>>(x2, Wih_f, bih_f, bhh_f, Wih_b, bih_b, bhh_b, pre);
    k_lstm2<<<2, 128, 0, stream>>>(pre, Whh_f, Whh_b, x3l);
    k_red<64><<<(NN + 511) / 512, 256, 0, stream>>>(x3l, stats + 384);
    k_x3<<<NN, 64, 0, stream>>>(x2, sc3W, sc3b, bn3g, bn3b, stats + 384, x3l);
    k_heads<<<NN, 64, 0, stream>>>(x3l, a1W, a1b, a2W, a2b, c1W, c1b, c2W, c2b, outp);
}

// Round 5
// 21392.708 us; speedup vs baseline: 1.4501x; 1.0311x over previous
//
#include <hip/hip_runtime.h>

#define NN 50000
#define NE 600000

typedef __attribute__((ext_vector_type(2))) float f2;
typedef __attribute__((ext_vector_type(4))) float f4;

// ---------------- workspace layout (bytes) ----------------
static const size_t OFF_DEG    = 0;                         // 2*NN ints (deg_out, deg_in)
static const size_t OFF_NRM_O  = (size_t)8 * NN;            // NN floats
static const size_t OFF_NRM_I  = (size_t)12 * NN;           // NN floats
static const size_t OFF_STATS  = (size_t)16 * NN;           // 512 floats
static const size_t OFF_ZONE   = 1048576;                   // 1 MiB aligned big zone
static const size_t OFF_H0   = OFF_ZONE + 0;                // NN*48*4
static const size_t OFF_AGG1 = OFF_ZONE + 9600000;          // NN*48*4
static const size_t OFF_X1   = OFF_ZONE + 19200000;         // NN*128*4 (y1 then x1 in-place)
static const size_t OFF_T2   = OFF_ZONE + 44800000;         // NN*64*4
static const size_t OFF_PRE  = OFF_ZONE + 0;                // [2][NN][128] overlays h0..t2 (dead by then)
static const size_t OFF_AGG2 = OFF_ZONE + 57600000;         // NN*64*4 (y2 in-place)
static const size_t OFF_X2   = OFF_ZONE + 70400000;         // NN*64*4
static const size_t OFF_X3L  = OFF_ZONE + 83200000;         // NN*64*4 (x3 in-place)

__global__ void k_deg(const int* __restrict__ src, const int* __restrict__ dst,
                      int* __restrict__ deg_out, int* __restrict__ deg_in) {
    int e = blockIdx.x * blockDim.x + threadIdx.x;
    if (e < NE) {
        atomicAdd(&deg_out[src[e]], 1);
        atomicAdd(&deg_in[dst[e]], 1);
    }
}

__global__ void k_h0(const float* __restrict__ x, const int* __restrict__ nid,
                     const float* __restrict__ emb,
                     const int* __restrict__ deg_out, const int* __restrict__ deg_in,
                     float* __restrict__ nrm_out, float* __restrict__ nrm_in,
                     float* __restrict__ h0) {
    int n = blockIdx.x * blockDim.x + threadIdx.x;
    if (n >= NN) return;
    nrm_out[n] = rsqrtf((float)(deg_out[n] + 1));
    nrm_in[n]  = rsqrtf((float)(deg_in[n] + 1));
    const float* xr = x + (size_t)n * 35;
    float* hr = h0 + (size_t)n * 48;
    #pragma unroll
    for (int k = 0; k < 35; k++) hr[k] = xr[k];
    const float* er = emb + (size_t)nid[n] * 10;
    #pragma unroll
    for (int k = 0; k < 10; k++) hr[35 + k] = er[k];
    hr[45] = 0.f; hr[46] = 0.f; hr[47] = 0.f;
}

__global__ void k_scatter1(const int* __restrict__ src, const int* __restrict__ dst,
                           const float* __restrict__ h0, const float* __restrict__ nrm_out,
                           float* __restrict__ agg1) {
    long long t = (long long)blockIdx.x * blockDim.x + threadIdx.x;
    int e = (int)(t >> 2), q = (int)(t & 3);
    if (e >= NE) return;
    int s = src[e], d = dst[e];
    float sc = nrm_out[s];
    const float4* hr = (const float4*)(h0 + (size_t)s * 48) + q * 3;
    float* ar = agg1 + (size_t)d * 48 + q * 12;
    #pragma unroll
    for (int i = 0; i < 3; i++) {
        float4 v = hr[i];
        atomicAdd(ar + i * 4 + 0, v.x * sc);
        atomicAdd(ar + i * 4 + 1, v.y * sc);
        atomicAdd(ar + i * 4 + 2, v.z * sc);
        atomicAdd(ar + i * 4 + 3, v.w * sc);
    }
}

__global__ void k_y1(const float* __restrict__ h0, const float* __restrict__ agg1,
                     const float* __restrict__ nrm_out, const float* __restrict__ nrm_in,
                     const float* __restrict__ W1, const float* __restrict__ b1,
                     float* __restrict__ y1) {
    __shared__ float v[48];
    int n = blockIdx.x, o = threadIdx.x;
    if (o < 48) {
        v[o] = (agg1[(size_t)n * 48 + o] + h0[(size_t)n * 48 + o] * nrm_out[n]) * nrm_in[n];
    }
    __syncthreads();
    float acc = b1[o];
    #pragma unroll
    for (int k = 0; k < 45; k++) acc += v[k] * W1[k * 128 + o];
    y1[(size_t)n * 128 + o] = acc;
}

template<int F>
__global__ void k_red(const float* __restrict__ y, float* __restrict__ stats) {
    const int parts = 256 / F;
    __shared__ float s1[256], s2[256];
    int tid = threadIdx.x;
    int o = tid % F, p = tid / F;
    float a = 0.f, b = 0.f;
    int n0 = blockIdx.x * 512;
    int n1 = n0 + 512; if (n1 > NN) n1 = NN;
    for (int n = n0 + p; n < n1; n += parts) {
        float v = y[(size_t)n * F + o];
        a += v; b += v * v;
    }
    s1[tid] = a; s2[tid] = b;
    __syncthreads();
    if (p == 0) {
        #pragma unroll
        for (int pp = 1; pp < parts; pp++) { a += s1[pp * F + o]; b += s2[pp * F + o]; }
        atomicAdd(&stats[o], a);
        atomicAdd(&stats[F + o], b);
    }
}

__global__ void k_x1(const float* __restrict__ h0, const float* __restrict__ sc1W,
                     const float* __restrict__ sc1b, const float* __restrict__ g,
                     const float* __restrict__ bb, const float* __restrict__ stats,
                     float* __restrict__ y1x1) {
    __shared__ float hr[48];
    int n = blockIdx.x, o = threadIdx.x;
    if (o < 48) hr[o] = h0[(size_t)n * 48 + o];
    __syncthreads();
    float mu = stats[o] * (1.f / NN);
    float var = stats[128 + o] * (1.f / NN) - mu * mu;
    float istd = rsqrtf(var + 1e-5f);
    float acc = sc1b[o];
    #pragma unroll
    for (int k = 0; k < 45; k++) acc += hr[k] * sc1W[o * 45 + k];
    float v = (y1x1[(size_t)n * 128 + o] - mu) * istd * g[o] + bb[o] + acc;
    y1x1[(size_t)n * 128 + o] = v > 0.f ? v : 0.f;
}

__global__ void k_t2(const float* __restrict__ x1, const float* __restrict__ W2,
                     const float* __restrict__ nrm_out, float* __restrict__ t2) {
    __shared__ float xr[128];
    int n = blockIdx.x, o = threadIdx.x;
    xr[o] = x1[(size_t)n * 128 + o];
    xr[o + 64] = x1[(size_t)n * 128 + o + 64];
    __syncthreads();
    float acc = 0.f;
    #pragma unroll
    for (int k = 0; k < 128; k++) acc += xr[k] * W2[k * 64 + o];
    t2[(size_t)n * 64 + o] = acc * nrm_out[n];
}

__global__ void k_scatter2(const int* __restrict__ src, const int* __restrict__ dst,
                           const float* __restrict__ t2, float* __restrict__ agg2) {
    long long t = (long long)blockIdx.x * blockDim.x + threadIdx.x;
    int e = (int)(t >> 2), q = (int)(t & 3);
    if (e >= NE) return;
    int s = src[e], d = dst[e];
    const float4* tr = (const float4*)(t2 + (size_t)s * 64) + q * 4;
    float* ar = agg2 + (size_t)d * 64 + q * 16;
    #pragma unroll
    for (int i = 0; i < 4; i++) {
        float4 v = tr[i];
        atomicAdd(ar + i * 4 + 0, v.x);
        atomicAdd(ar + i * 4 + 1, v.y);
        atomicAdd(ar + i * 4 + 2, v.z);
        atomicAdd(ar + i * 4 + 3, v.w);
    }
}

__global__ void k_y2(float* __restrict__ agg2, const float* __restrict__ t2,
                     const float* __restrict__ nrm_in, const float* __restrict__ b2) {
    int i = blockIdx.x * blockDim.x + threadIdx.x;
    if (i >= NN * 64) return;
    int n = i >> 6, o = i & 63;
    agg2[i] = (agg2[i] + t2[i]) * nrm_in[n] + b2[o];
}

__global__ void k_x2(const float* __restrict__ x1, const float* __restrict__ y2,
                     const float* __restrict__ sc2W, const float* __restrict__ sc2b,
                     const float* __restrict__ g, const float* __restrict__ bb,
                     const float* __restrict__ stats, float* __restrict__ x2) {
    __shared__ float xr[128];
    int n = blockIdx.x, o = threadIdx.x;
    xr[o] = x1[(size_t)n * 128 + o];
    xr[o + 64] = x1[(size_t)n * 128 + o + 64];
    __syncthreads();
    float mu = stats[o] * (1.f / NN);
    float var = stats[64 + o] * (1.f / NN) - mu * mu;
    float istd = rsqrtf(var + 1e-5f);
    float acc = sc2b[o];
    #pragma unroll
    for (int k = 0; k < 128; k++) acc += xr[k] * sc2W[o * 128 + k];
    float v = (y2[(size_t)n * 64 + o] - mu) * istd * g[o] + bb[o] + acc;
    x2[(size_t)n * 64 + o] = v > 0.f ? v : 0.f;
}

__global__ void k_pre(const float* __restrict__ x2,
                      const float* __restrict__ Wf, const float* __restrict__ bif, const float* __restrict__ bhf,
                      const float* __restrict__ Wb, const float* __restrict__ bib, const float* __restrict__ bhb,
                      float* __restrict__ pre) {
    __shared__ float xr[64];
    int n = blockIdx.x, t = threadIdx.x;
    int j = t & 127, dir = t >> 7;
    if (t < 64) xr[t] = x2[(size_t)n * 64 + t];
    __syncthreads();
    const float* W = dir ? Wb : Wf;
    float acc = dir ? (bib[j] + bhb[j]) : (bif[j] + bhf[j]);
    #pragma unroll
    for (int k = 0; k < 64; k++) acc += xr[k] * W[j * 64 + k];
    pre[((size_t)dir * NN + n) * 128 + j] = acc;
}

// Single wave per direction. Lane j (j<32): rows j (i) and 64+j (g).
// Lane 32+j: rows 32+j (f) and 96+j (o). One shfl_xor carries u=i*g to the
// upper half, which owns (c,h). h broadcast: 1 LDS write + 8 broadcast
// ds_read_b128 per step — no barriers (single wave, in-order DS pipe).
// Weights pinned in VGPRs via empty asm so the compiler can't rematerialize
// the global loads inside the 50k-step loop (round-1 failure mode, VGPR=76).
__global__ void __launch_bounds__(64, 1)
k_lstm3(const float* __restrict__ pre, const float* __restrict__ Whh_f,
        const float* __restrict__ Whh_b, float* __restrict__ x3l) {
    const int dir = blockIdx.x;
    const float* __restrict__ P = pre + (size_t)dir * NN * 128;
    const float* __restrict__ Whh = dir ? Whh_b : Whh_f;
    const int lane = threadIdx.x;
    const int j = lane & 31;
    const bool lower = lane < 32;

    __shared__ f4 hbuf[2][8];   // [buf][32 floats]

    f2 wa[16], wb[16];
    #pragma unroll
    for (int m = 0; m < 16; m++) {
        wa[m] = ((const f2*)(Whh + (size_t)lane * 32))[m];
        wb[m] = ((const f2*)(Whh + (size_t)(lane + 64) * 32))[m];
    }
    #pragma unroll
    for (int m = 0; m < 16; m++) {
        asm volatile("" : "+v"(wa[m]), "+v"(wb[m]));
    }

    if (lower) ((float*)hbuf[0])[j] = 0.f;   // h input for step 0
    float c = 0.f;

    float pa[8], pb[8], nxa[8], nxb[8];
    #pragma unroll
    for (int k = 0; k < 8; k++) {
        int t = dir ? (NN - 1 - k) : k;
        pa[k] = P[(size_t)t * 128 + lane];
        pb[k] = P[(size_t)t * 128 + 64 + lane];
    }

    for (int base = 0; base < NN; base += 8) {
        int nxt = (base + 8 < NN) ? base + 8 : base;
        #pragma unroll
        for (int k = 0; k < 8; k++) {
            int s = nxt + k;
            int t = dir ? (NN - 1 - s) : s;
            nxa[k] = P[(size_t)t * 128 + lane];
            nxb[k] = P[(size_t)t * 128 + 64 + lane];
        }
        #pragma unroll
        for (int k = 0; k < 8; k++) {
            const int s = base + k;
            const int b = s & 1;
            f2 a0 = {0.f, 0.f}, a1 = {0.f, 0.f};
            f2 b0 = {0.f, 0.f}, b1 = {0.f, 0.f};
            #pragma unroll
            for (int m = 0; m < 8; m++) {
                f4 hv = hbuf[b][m];
                f2 hlo = hv.xy, hhi = hv.zw;
                a0 += wa[2 * m] * hlo;
                a1 += wa[2 * m + 1] * hhi;
                b0 += wb[2 * m] * hlo;
                b1 += wb[2 * m + 1] * hhi;
            }
            f2 ra = a0 + a1, rb = b0 + b1;
            float ga = pa[k] + ra.x + ra.y;
            float gb = pb[k] + rb.x + rb.y;
            float act_a = 1.f / (1.f + __expf(-ga));              // i (lower) / f (upper)
            float eb = __expf(lower ? -2.f * gb : -gb);
            float sb = 1.f / (1.f + eb);
            float act_b = lower ? 2.f * sb - 1.f : sb;            // g (lower) / o (upper)
            float u = act_a * act_b;                              // i*g in lower half
            float xu = __shfl_xor(u, 32);
            c = act_a * c + xu;                                   // valid in upper: f*c + i*g
            float th = 2.f / (1.f + __expf(-2.f * c)) - 1.f;      // tanh(c)
            float h = act_b * th;                                 // valid in upper: o*tanh(c)
            if (!lower) {
                ((float*)hbuf[b ^ 1])[j] = h;                     // next step's h input
                int t = dir ? (NN - 1 - s) : s;
                x3l[(size_t)t * 64 + dir * 32 + j] = h;
            }
        }
        #pragma unroll
        for (int k = 0; k < 8; k++) { pa[k] = nxa[k]; pb[k] = nxb[k]; }
    }
}

__global__ void k_x3(const float* __restrict__ x2, const float* __restrict__ sc3W,
                     const float* __restrict__ sc3b, const float* __restrict__ g,
                     const float* __restrict__ bb, const float* __restrict__ stats,
                     float* __restrict__ x3l) {
    __shared__ float xr[64];
    int n = blockIdx.x, o = threadIdx.x;
    xr[o] = x2[(size_t)n * 64 + o];
    __syncthreads();
    float mu = stats[o] * (1.f / NN);
    float var = stats[64 + o] * (1.f / NN) - mu * mu;
    float istd = rsqrtf(var + 1e-5f);
    float acc = sc3b[o];
    #pragma unroll
    for (int k = 0; k < 64; k++) acc += xr[k] * sc3W[o * 64 + k];
    float v = (x3l[(size_t)n * 64 + o] - mu) * istd * g[o] + bb[o] + acc;
    x3l[(size_t)n * 64 + o] = v > 0.f ? v : 0.f;
}

__global__ void k_heads(const float* __restrict__ x3,
                        const float* __restrict__ a1W, const float* __restrict__ a1b,
                        const float* __restrict__ a2W, const float* __restrict__ a2b,
                        const float* __restrict__ c1W, const float* __restrict__ c1b,
                        const float* __restrict__ c2W, const float* __restrict__ c2b,
                        float* __restrict__ outp) {
    __shared__ float xr[64];
    int n = blockIdx.x, o = threadIdx.x;
    xr[o] = x3[(size_t)n * 64 + o];
    __syncthreads();
    float ta = a1b[o], tc = c1b[o];
    #pragma unroll
    for (int k = 0; k < 64; k++) {
        float xv = xr[k];
        ta += xv * a1W[o * 64 + k];
        tc += xv * c1W[o * 64 + k];
    }
    ta = ta > 0.f ? ta : 0.f;
    tc = tc > 0.f ? tc : 0.f;
    float va = ta * a2W[o], vc = tc * c2W[o];
    #pragma unroll
    for (int off = 32; off; off >>= 1) {
        va += __shfl_down(va, off);
        vc += __shfl_down(vc, off);
    }
    if (o == 0) {
        outp[n] = va + a2b[0];
        outp[NN + n] = vc + c2b[0];
    }
}

extern "C" void kernel_launch(void* const* d_in, const int* in_sizes, int n_in,
                              void* d_out, int out_size, void* d_ws, size_t ws_size,
                              hipStream_t stream) {
    const int*   src   = (const int*)  d_in[0];
    const int*   dst   = (const int*)  d_in[1];
    const float* x     = (const float*)d_in[2];
    const int*   nid   = (const int*)  d_in[3];
    const float* emb   = (const float*)d_in[4];
    const float* W1    = (const float*)d_in[5];
    const float* b1    = (const float*)d_in[6];
    const float* W2    = (const float*)d_in[7];
    const float* b2    = (const float*)d_in[8];
    const float* bn1g  = (const float*)d_in[9];
    const float* bn1b  = (const float*)d_in[10];
    const float* bn2g  = (const float*)d_in[11];
    const float* bn2b  = (const float*)d_in[12];
    const float* bn3g  = (const float*)d_in[13];
    const float* bn3b  = (const float*)d_in[14];
    const float* sc1W  = (const float*)d_in[15];
    const float* sc1b  = (const float*)d_in[16];
    const float* sc2W  = (const float*)d_in[17];
    const float* sc2b  = (const float*)d_in[18];
    const float* sc3W  = (const float*)d_in[19];
    const float* sc3b  = (const float*)d_in[20];
    const float* Wih_f = (const float*)d_in[21];
    const float* Whh_f = (const float*)d_in[22];
    const float* bih_f = (const float*)d_in[23];
    const float* bhh_f = (const float*)d_in[24];
    const float* Wih_b = (const float*)d_in[25];
    const float* Whh_b = (const float*)d_in[26];
    const float* bih_b = (const float*)d_in[27];
    const float* bhh_b = (const float*)d_in[28];
    const float* a1W   = (const float*)d_in[29];
    const float* a1b   = (const float*)d_in[30];
    const float* a2W   = (const float*)d_in[31];
    const float* a2b   = (const float*)d_in[32];
    const float* c1W   = (const float*)d_in[33];
    const float* c1b   = (const float*)d_in[34];
    const float* c2W   = (const float*)d_in[35];
    const float* c2b   = (const float*)d_in[36];
    float* outp = (float*)d_out;
    char* ws = (char*)d_ws;

    int*   deg_out = (int*)  (ws + OFF_DEG);
    int*   deg_in  = (int*)  (ws + OFF_DEG + 4 * (size_t)NN);
    float* nrm_out = (float*)(ws + OFF_NRM_O);
    float* nrm_in  = (float*)(ws + OFF_NRM_I);
    float* stats   = (float*)(ws + OFF_STATS);
    float* h0   = (float*)(ws + OFF_H0);
    float* agg1 = (float*)(ws + OFF_AGG1);
    float* x1   = (float*)(ws + OFF_X1);
    float* t2   = (float*)(ws + OFF_T2);
    float* pre  = (float*)(ws + OFF_PRE);
    float* agg2 = (float*)(ws + OFF_AGG2);
    float* x2   = (float*)(ws + OFF_X2);
    float* x3l  = (float*)(ws + OFF_X3L);

    hipMemsetAsync(ws + OFF_DEG, 0, 8 * (size_t)NN, stream);
    hipMemsetAsync(ws + OFF_STATS, 0, 512 * 4, stream);
    hipMemsetAsync(ws + OFF_AGG1, 0, (size_t)NN * 48 * 4, stream);
    hipMemsetAsync(ws + OFF_AGG2, 0, (size_t)NN * 64 * 4, stream);

    k_deg<<<(NE + 255) / 256, 256, 0, stream>>>(src, dst, deg_out, deg_in);
    k_h0<<<(NN + 255) / 256, 256, 0, stream>>>(x, nid, emb, deg_out, deg_in, nrm_out, nrm_in, h0);
    k_scatter1<<<(4 * NE) / 256, 256, 0, stream>>>(src, dst, h0, nrm_out, agg1);
    k_y1<<<NN, 128, 0, stream>>>(h0, agg1, nrm_out, nrm_in, W1, b1, x1);
    k_red<128><<<(NN + 511) / 512, 256, 0, stream>>>(x1, stats);
    k_x1<<<NN, 128, 0, stream>>>(h0, sc1W, sc1b, bn1g, bn1b, stats, x1);
    k_t2<<<NN, 64, 0, stream>>>(x1, W2, nrm_out, t2);
    k_scatter2<<<(4 * NE) / 256, 256, 0, stream>>>(src, dst, t2, agg2);
    k_y2<<<(NN * 64 + 255) / 256, 256, 0, stream>>>(agg2, t2, nrm_in, b2);
    k_red<64><<<(NN + 511) / 512, 256, 0, stream>>>(agg2, stats + 256);
    k_x2<<<NN, 64, 0, stream>>>(x1, agg2, sc2W, sc2b, bn2g, bn2b, stats + 256, x2);
    k_pre<<<NN, 256, 0, stream>>>(x2, Wih_f, bih_f, bhh_f, Wih_b, bih_b, bhh_b, pre);
    k_lstm3<<<2, 64, 0, stream>>>(pre, Whh_f, Whh_b, x3l);
    k_red<64><<<(NN + 511) / 512, 256, 0, stream>>>(x3l, stats + 384);
    k_x3<<<NN, 64, 0, stream>>>(x2, sc3W, sc3b, bn3g, bn3b, stats + 384, x3l);
    k_heads<<<NN, 64, 0, stream>>>(x3l, a1W, a1b, a2W, a2b, c1W, c1b, c2W, c2b, outp);
}